// Round 1
// baseline (583.397 us; speedup 1.0000x reference)
//
#include <hip/hip_runtime.h>
#include <math.h>

#define N_USERS 8192
#define DIMS    128
#define EDGES   262144
#define KCAND   131072
#define NTOT    (EDGES + KCAND)      // 393216
#define CAP     256                  // per-row candidate buffer capacity
#define COS_THR 0.3f

// ---------------------------------------------------------------------------
// 1) normalize: replicate numpy pairwise-sum norm (8 accumulators + tree),
//    correctly-rounded sqrt via double, precise fp32 division.
// ---------------------------------------------------------------------------
__global__ __launch_bounds__(256) void normalize_k(const float* __restrict__ x,
                                                   float* __restrict__ u) {
#pragma clang fp contract(off)
  int i = blockIdx.x * 256 + threadIdx.x;
  if (i >= N_USERS) return;
  const float* r = x + (size_t)i * DIMS;
  float a[8];
#pragma unroll
  for (int j = 0; j < 8; ++j) { float t = r[j]; a[j] = t * t; }
  for (int b8 = 8; b8 < DIMS; b8 += 8) {
#pragma unroll
    for (int j = 0; j < 8; ++j) { float t = r[b8 + j]; a[j] = a[j] + t * t; }
  }
  float s = ((a[0] + a[1]) + (a[2] + a[3])) + ((a[4] + a[5]) + (a[6] + a[7]));
  float n = (float)sqrt((double)s);
  n = fmaxf(n, 1e-12f);
  for (int k = 0; k < DIMS; ++k) u[(size_t)i * DIMS + k] = r[k] / n;
}

// ---------------------------------------------------------------------------
// 2) exclusion bitmask from nonzero_idx (8192 x 256 words)
// ---------------------------------------------------------------------------
__global__ __launch_bounds__(256) void build_excl(const int* __restrict__ nz,
                                                  unsigned* __restrict__ excl) {
  int t = blockIdx.x * 256 + threadIdx.x;
  if (t >= EDGES) return;
  int i = nz[2 * t], j = nz[2 * t + 1];
  atomicOr(&excl[(size_t)i * 256 + (j >> 5)], 1u << (j & 31));
}

// ---------------------------------------------------------------------------
// 3) pass_a: fp32 cos GEMM, 16 rows/block, 256-col j-tiles swept in order.
//    4x4 register tile per thread; sequential-k fmaf accumulation.
//    After each j-tile: ballot-compact candidates per row, in column order,
//    into per-row buffers (rowj/rowv) + running counts.
// ---------------------------------------------------------------------------
__global__ __launch_bounds__(256) void pass_a(const float* __restrict__ u,
                                              const unsigned* __restrict__ excl,
                                              int* __restrict__ rowj,
                                              float* __restrict__ rowv,
                                              int* __restrict__ row_cnt) {
  __shared__ float rowsL[16][132];   // [row][k], stride 132 keeps float4 alignment
  __shared__ float colsL[32][260];   // [k within chunk][col], k-major

  const int tid  = threadIdx.x;
  const int lane = tid & 63;
  const int wv   = tid >> 6;              // wave 0..3 owns rows 4w..4w+3
  const int rowbase = blockIdx.x * 16;

  // stage this block's 16 rows of u
  for (int idx = tid; idx < 16 * 32; idx += 256) {
    int r = idx >> 5, c4 = idx & 31;
    float4 f = ((const float4*)(u + (size_t)(rowbase + r) * DIMS))[c4];
    *(float4*)&rowsL[r][c4 * 4] = f;
  }

  int cnt[4] = {0, 0, 0, 0};
  const int gi0 = rowbase + wv * 4;
  const unsigned long long below = (1ull << lane) - 1ull;

  for (int jb = 0; jb < N_USERS; jb += 256) {
    float acc[4][4];
#pragma unroll
    for (int rr = 0; rr < 4; ++rr)
#pragma unroll
      for (int cc = 0; cc < 4; ++cc) acc[rr][cc] = 0.f;

    for (int kc = 0; kc < DIMS; kc += 32) {
      __syncthreads();  // protects colsL reuse (and rowsL on first pass)
      {
        const int ksub = (tid & 7) * 4;
        const int colbase = tid >> 3;
#pragma unroll
        for (int it = 0; it < 8; ++it) {
          int col = colbase + it * 32;
          float4 f = *(const float4*)(u + (size_t)(jb + col) * DIMS + kc + ksub);
          colsL[ksub + 0][col] = f.x;
          colsL[ksub + 1][col] = f.y;
          colsL[ksub + 2][col] = f.z;
          colsL[ksub + 3][col] = f.w;
        }
      }
      __syncthreads();
#pragma unroll
      for (int k4 = 0; k4 < 32; k4 += 4) {
        float rv[4][4], cv[4][4];
#pragma unroll
        for (int rr = 0; rr < 4; ++rr) {
          float4 f = *(const float4*)&rowsL[wv * 4 + rr][kc + k4];  // broadcast
          rv[rr][0] = f.x; rv[rr][1] = f.y; rv[rr][2] = f.z; rv[rr][3] = f.w;
        }
#pragma unroll
        for (int kk = 0; kk < 4; ++kk) {
          float4 f = *(const float4*)&colsL[k4 + kk][lane * 4];
          cv[kk][0] = f.x; cv[kk][1] = f.y; cv[kk][2] = f.z; cv[kk][3] = f.w;
        }
#pragma unroll
        for (int kk = 0; kk < 4; ++kk)
#pragma unroll
          for (int rr = 0; rr < 4; ++rr)
#pragma unroll
            for (int cc = 0; cc < 4; ++cc)
              acc[rr][cc] = fmaf(rv[rr][kk], cv[kk][cc], acc[rr][cc]);
      }
    }

    // ---- candidate scan for this j-tile (wave w handles its own 4 rows) ----
    const int jcol0 = jb + lane * 4;
#pragma unroll
    for (int rr = 0; rr < 4; ++rr) {
      const int gi = gi0 + rr;
      unsigned word = excl[(size_t)gi * 256 + (jb >> 5) + (lane >> 3)];
      int bitbase = (lane & 7) * 4;
      bool pred[4];
      unsigned long long m[4];
#pragma unroll
      for (int cc = 0; cc < 4; ++cc) {
        float v = acc[rr][cc];
        pred[cc] = (v > COS_THR) && !((word >> (bitbase + cc)) & 1u) &&
                   (jcol0 + cc != gi);
        m[cc] = __ballot(pred[cc]);
      }
      int before = __popcll(m[0] & below) + __popcll(m[1] & below) +
                   __popcll(m[2] & below) + __popcll(m[3] & below);
      int base = cnt[rr] + before;
      int sub = 0;
#pragma unroll
      for (int cc = 0; cc < 4; ++cc) {
        if (pred[cc]) {
          int idx = base + sub;
          if (idx < CAP) {
            rowj[(size_t)gi * CAP + idx] = jcol0 + cc;
            rowv[(size_t)gi * CAP + idx] = acc[rr][cc];
          }
          ++sub;
        }
      }
      cnt[rr] += __popcll(m[0]) + __popcll(m[1]) + __popcll(m[2]) + __popcll(m[3]);
    }
  }

  if (lane == 0) {
#pragma unroll
    for (int rr = 0; rr < 4; ++rr) row_cnt[gi0 + rr] = min(cnt[rr], CAP);
  }
}

// ---------------------------------------------------------------------------
// 4) exclusive prefix scan over 8192 row counts (single block)
// ---------------------------------------------------------------------------
__global__ __launch_bounds__(256) void scan_rows(const int* __restrict__ cnt,
                                                 int* __restrict__ off) {
  __shared__ int s[256];
  __shared__ int carry;
  int tid = threadIdx.x;
  if (tid == 0) carry = 0;
  __syncthreads();
  for (int c = 0; c < N_USERS / 256; ++c) {
    int v = cnt[c * 256 + tid];
    int x = v;
    s[tid] = x;
    __syncthreads();
    for (int d = 1; d < 256; d <<= 1) {
      int y = (tid >= d) ? s[tid - d] : 0;
      __syncthreads();
      x += y;
      s[tid] = x;
      __syncthreads();
    }
    int cbase = carry;
    off[c * 256 + tid] = cbase + x - v;
    int tot = s[255];
    __syncthreads();
    if (tid == 0) carry = cbase + tot;
    __syncthreads();
  }
  if (tid == 0) off[N_USERS] = carry;
}

// ---------------------------------------------------------------------------
// 5) compact per-row buffers into the global candidate list (row-major order)
// ---------------------------------------------------------------------------
__global__ __launch_bounds__(256) void compact_rows(const int* __restrict__ row_cnt,
                                                    const int* __restrict__ row_off,
                                                    const int* __restrict__ rowj,
                                                    const float* __restrict__ rowv,
                                                    int* __restrict__ cand_i,
                                                    int* __restrict__ cand_j,
                                                    float* __restrict__ cand_v) {
  int i = blockIdx.x * 256 + threadIdx.x;
  if (i >= N_USERS) return;
  int n = row_cnt[i], off = row_off[i];
  for (int t = 0; t < n; ++t) {
    int o = off + t;
    if (o < KCAND) {
      cand_i[o] = i;
      cand_j[o] = rowj[(size_t)i * CAP + t];
      cand_v[o] = rowv[(size_t)i * CAP + t];
    }
  }
}

// 5b) pad the tail [M, K): nonzero fill_value=0, cand_val = cos[0,0] = -1
__global__ __launch_bounds__(256) void pad_cands(const int* __restrict__ row_off,
                                                 int* __restrict__ cand_i,
                                                 int* __restrict__ cand_j,
                                                 float* __restrict__ cand_v) {
  int t = blockIdx.x * 256 + threadIdx.x;
  if (t >= KCAND) return;
  int M = row_off[N_USERS];
  if (t >= M) { cand_i[t] = 0; cand_j[t] = 0; cand_v[t] = -1.0f; }
}

// ---------------------------------------------------------------------------
// 6) finalize: logits (sequential 256-term fmaf chain, matching BLAS order),
//    gumbel argmax, weights, all three outputs (indices written as floats).
// ---------------------------------------------------------------------------
__global__ __launch_bounds__(256) void finalize_k(const float* __restrict__ ue,
                                                  const float* __restrict__ W,
                                                  const float* __restrict__ b,
                                                  const float* __restrict__ g,
                                                  const int* __restrict__ nz,
                                                  const int* __restrict__ cand_i,
                                                  const int* __restrict__ cand_j,
                                                  const float* __restrict__ cand_v,
                                                  float* __restrict__ out) {
  __shared__ float Ws[512];
  int tid = threadIdx.x;
  Ws[tid] = W[tid];
  Ws[tid + 256] = W[tid + 256];
  __syncthreads();

  int p = blockIdx.x * 256 + tid;
  if (p >= NTOT) return;

  int i, j;
  float wgt;
  if (p < EDGES) {
    i = nz[2 * p];
    j = nz[2 * p + 1];
    wgt = 1.0f;
  } else {
    int q = p - EDGES;
    i = cand_i[q];
    j = cand_j[q];
    wgt = fmaxf(cand_v[q], 0.0f);
  }

  const float4* ri = (const float4*)(ue + (size_t)i * DIMS);
  const float4* rj = (const float4*)(ue + (size_t)j * DIMS);
  float l0 = 0.f, l1 = 0.f;
#pragma unroll
  for (int kk = 0; kk < 32; ++kk) {
    float4 a = ri[kk];
    l0 = fmaf(a.x, Ws[kk * 4 + 0], l0);
    l0 = fmaf(a.y, Ws[kk * 4 + 1], l0);
    l0 = fmaf(a.z, Ws[kk * 4 + 2], l0);
    l0 = fmaf(a.w, Ws[kk * 4 + 3], l0);
    l1 = fmaf(a.x, Ws[256 + kk * 4 + 0], l1);
    l1 = fmaf(a.y, Ws[256 + kk * 4 + 1], l1);
    l1 = fmaf(a.z, Ws[256 + kk * 4 + 2], l1);
    l1 = fmaf(a.w, Ws[256 + kk * 4 + 3], l1);
  }
#pragma unroll
  for (int kk = 0; kk < 32; ++kk) {
    float4 a = rj[kk];
    l0 = fmaf(a.x, Ws[128 + kk * 4 + 0], l0);
    l0 = fmaf(a.y, Ws[128 + kk * 4 + 1], l0);
    l0 = fmaf(a.z, Ws[128 + kk * 4 + 2], l0);
    l0 = fmaf(a.w, Ws[128 + kk * 4 + 3], l0);
    l1 = fmaf(a.x, Ws[384 + kk * 4 + 0], l1);
    l1 = fmaf(a.y, Ws[384 + kk * 4 + 1], l1);
    l1 = fmaf(a.z, Ws[384 + kk * 4 + 2], l1);
    l1 = fmaf(a.w, Ws[384 + kk * 4 + 3], l1);
  }
  l0 += b[0];
  l1 += b[1];

  float s0 = l0 + g[2 * p];
  float s1 = l1 + g[2 * p + 1];
  // softmax+argmax is monotone; argmax ties -> index 0 -> retain = 1
  float w = (s0 >= s1) ? wgt : 0.0f;

  // out0: gumbel_01 [0, NTOT)
  // out1: gumbel_retain_w [NTOT, 3*NTOT)  (w stacked twice)
  // out2: pair_idx as floats [3*NTOT, 5*NTOT)
  out[p] = w;
  out[NTOT + p] = w;
  out[2 * NTOT + p] = w;
  out[3 * NTOT + 2 * p + 0] = (float)i;
  out[3 * NTOT + 2 * p + 1] = (float)j;
}

// ---------------------------------------------------------------------------
extern "C" void kernel_launch(void* const* d_in, const int* in_sizes, int n_in,
                              void* d_out, int out_size, void* d_ws, size_t ws_size,
                              hipStream_t stream) {
  (void)in_sizes; (void)n_in; (void)out_size; (void)ws_size;

  const float* user_emb = (const float*)d_in[0];
  const float* W        = (const float*)d_in[1];
  const float* b        = (const float*)d_in[2];
  const float* gnoise   = (const float*)d_in[3];
  const int*   nz       = (const int*)d_in[4];
  float* out = (float*)d_out;

  char* ws = (char*)d_ws;
  // ws layout (bytes)
  float*    u        = (float*)(ws + 0);                     //  4 MB
  unsigned* excl     = (unsigned*)(ws + 4194304);            //  8 MB
  int*      rowj     = (int*)(ws + 12582912);                //  8 MB
  float*    rowv     = (float*)(ws + 20971520);              //  8 MB
  int*      row_cnt  = (int*)(ws + 29360128);                // 32 KB
  int*      row_off  = (int*)(ws + 29392896);                // 8193 ints
  int*      cand_i   = (int*)(ws + 29425920);                // 512 KB
  int*      cand_j   = (int*)(ws + 29950208);                // 512 KB
  float*    cand_v   = (float*)(ws + 30474496);              // 512 KB

  hipMemsetAsync(excl, 0, (size_t)N_USERS * 256 * sizeof(unsigned), stream);
  hipMemsetAsync(row_cnt, 0, (size_t)N_USERS * sizeof(int), stream);

  normalize_k<<<N_USERS / 256, 256, 0, stream>>>(user_emb, u);
  build_excl<<<EDGES / 256, 256, 0, stream>>>(nz, excl);
  pass_a<<<N_USERS / 16, 256, 0, stream>>>(u, excl, rowj, rowv, row_cnt);
  scan_rows<<<1, 256, 0, stream>>>(row_cnt, row_off);
  compact_rows<<<N_USERS / 256, 256, 0, stream>>>(row_cnt, row_off, rowj, rowv,
                                                  cand_i, cand_j, cand_v);
  pad_cands<<<KCAND / 256, 256, 0, stream>>>(row_off, cand_i, cand_j, cand_v);
  finalize_k<<<NTOT / 256, 256, 0, stream>>>(u /*unused*/ == u ? user_emb : user_emb,
                                             W, b, gnoise, nz,
                                             cand_i, cand_j, cand_v, out);
}